// Round 3
// baseline (998.761 us; speedup 1.0000x reference)
//
#include <hip/hip_runtime.h>
#include <stdint.h>

#define D_MODEL 1024
#define D_FF    4096
#define NE      8
#define T_TOK   4096
#define R_TOT   8192   // T_TOK * TOP_K, always exact (top-2 of 8 distinct)

typedef float f32x4 __attribute__((ext_vector_type(4)));
typedef __bf16 bf16x8 __attribute__((ext_vector_type(8)));
typedef unsigned short ushort_t;

__device__ __forceinline__ ushort_t f2bf(float f) {
    unsigned int u = __float_as_uint(f);
    u += 0x7FFFu + ((u >> 16) & 1u);   // round-to-nearest-even
    return (ushort_t)(u >> 16);
}

// async global->LDS, 16B per lane. Pass a WAVE-UNIFORM lds base; HW adds lane*16.
__device__ __forceinline__ void async16(const void* g, const void* l) {
    __builtin_amdgcn_global_load_lds(
        (const __attribute__((address_space(1))) unsigned int*)(uintptr_t)g,
        (__attribute__((address_space(3))) unsigned int*)(uintptr_t)l,
        16, 0, 0);
}

// ---------------- gate: one wave per token ----------------
__global__ __launch_bounds__(256) void k_gate(
    const float* __restrict__ x, const float* __restrict__ Wg, const float* __restrict__ bg,
    int* __restrict__ topi, float* __restrict__ topw, int* __restrict__ counts)
{
    int wave = threadIdx.x >> 6, lane = threadIdx.x & 63;
    int t = blockIdx.x * 4 + wave;
    const float* xr = x + (size_t)t * D_MODEL;
    float acc[NE];
#pragma unroll
    for (int e = 0; e < NE; ++e) acc[e] = 0.f;
#pragma unroll
    for (int i = 0; i < D_MODEL / 64; ++i) {
        int k = i * 64 + lane;
        float xv = xr[k];
        const float4* wgp = (const float4*)(Wg + (size_t)k * NE);
        float4 w0 = wgp[0], w1 = wgp[1];
        acc[0] += xv * w0.x; acc[1] += xv * w0.y; acc[2] += xv * w0.z; acc[3] += xv * w0.w;
        acc[4] += xv * w1.x; acc[5] += xv * w1.y; acc[6] += xv * w1.z; acc[7] += xv * w1.w;
    }
#pragma unroll
    for (int off = 32; off >= 1; off >>= 1)
#pragma unroll
        for (int e = 0; e < NE; ++e) acc[e] += __shfl_down(acc[e], off, 64);
    if (lane == 0) {
        float l[NE], m = -1e30f;
#pragma unroll
        for (int e = 0; e < NE; ++e) { l[e] = acc[e] + bg[e]; m = fmaxf(m, l[e]); }
        float p[NE], Z = 0.f;
#pragma unroll
        for (int e = 0; e < NE; ++e) { p[e] = __expf(l[e] - m); Z += p[e]; }
        float invZ = 1.f / Z;
        int i0 = 0; float v0 = -1.f;
#pragma unroll
        for (int e = 0; e < NE; ++e) { p[e] *= invZ; if (p[e] > v0) { v0 = p[e]; i0 = e; } }
        int i1 = 0; float v1 = -1.f;
#pragma unroll
        for (int e = 0; e < NE; ++e) { if (e != i0 && p[e] > v1) { v1 = p[e]; i1 = e; } }
        float denom = 1.f / (v0 + v1 + 1e-6f);
        topi[t * 2 + 0] = i0; topi[t * 2 + 1] = i1;
        topw[t * 2 + 0] = v0 * denom; topw[t * 2 + 1] = v1 * denom;
        atomicAdd(&counts[i0], 1); atomicAdd(&counts[i1], 1);
    }
}

// ---------------- tiny scan ----------------
__global__ void k_scan(const int* __restrict__ counts, int* __restrict__ offsets,
                       int* __restrict__ cursors)
{
    if (threadIdx.x == 0) {
        int acc = 0;
        for (int e = 0; e < NE; ++e) { offsets[e] = acc; cursors[e] = acc; acc += counts[e]; }
    }
}

// ---------------- scatter tokens into expert buckets ----------------
__global__ __launch_bounds__(256) void k_scatter(
    const int* __restrict__ topi, const float* __restrict__ topw,
    int* __restrict__ cursors, int* __restrict__ btok, float* __restrict__ bw)
{
    int t = blockIdx.x * 256 + threadIdx.x;
#pragma unroll
    for (int k = 0; k < 2; ++k) {
        int e = topi[t * 2 + k];
        int p = atomicAdd(&cursors[e], 1);
        btok[p] = t;
        bw[p] = topw[t * 2 + k];
    }
}

// ---------------- gather x rows (bucket order) + fp32->bf16 ----------------
__global__ __launch_bounds__(256) void k_gather(
    const float* __restrict__ x, const int* __restrict__ btok, ushort_t* __restrict__ Xg)
{
    int i = blockIdx.x;
    int t = btok[i];
    float4 v = ((const float4*)(x + (size_t)t * D_MODEL))[threadIdx.x];
    ushort4 o;
    o.x = f2bf(v.x); o.y = f2bf(v.y); o.z = f2bf(v.z); o.w = f2bf(v.w);
    ((ushort4*)(Xg + (size_t)i * D_MODEL))[threadIdx.x] = o;
}

// ---------------- weight transpose+convert: W[e][K][N] fp32 -> Wt[e][N][K] bf16 ----------------
__global__ __launch_bounds__(256) void k_transpose(
    const float* __restrict__ W, ushort_t* __restrict__ Wt, int K, int N)
{
    __shared__ ushort_t tile[64 * 72];
    int e = blockIdx.z;
    const float* We = W + (size_t)e * K * N;
    ushort_t* Wte = Wt + (size_t)e * K * N;
    int nb = blockIdx.x * 64, kb = blockIdx.y * 64;
    int tn4 = (threadIdx.x & 15) * 4;
    int tk = threadIdx.x >> 4;
#pragma unroll
    for (int r = 0; r < 4; ++r) {
        int k = r * 16 + tk;
        float4 v = *(const float4*)(We + (size_t)(kb + k) * N + nb + tn4);
        tile[(tn4 + 0) * 72 + k] = f2bf(v.x);
        tile[(tn4 + 1) * 72 + k] = f2bf(v.y);
        tile[(tn4 + 2) * 72 + k] = f2bf(v.z);
        tile[(tn4 + 3) * 72 + k] = f2bf(v.w);
    }
    __syncthreads();
#pragma unroll
    for (int c = 0; c < 4; ++c) {
        int chunk = c * 256 + threadIdx.x;
        int n = chunk >> 4, kc = (chunk & 15) * 4;
        ushort4 o = *(const ushort4*)&tile[n * 72 + kc];
        *(ushort4*)(Wte + (size_t)(nb + n) * K + kb + kc) = o;
    }
}

// LDS tile layout (BK=32): 128 rows x 32 elems (64 B/row). The 4 16B-chunks of
// row r are XOR-swizzled: chunk c stored at slot c ^ ((r>>1)&3).
// ds_read bank = 16*(row&1) + 4*slot -> exactly 2 lanes/bank (free, m136).
// Double-buffered: prefetch tile k+1 issued right after the barrier releasing
// compute on tile k; its latency hides under the MFMA phase. ONE barrier/iter.

// ---------------- grouped GEMM1: H = silu(Xg@W1 + b1) * (Xg@W3 + b3) ----------------
__global__ __launch_bounds__(256, 2) void k_gemm1(
    const ushort_t* __restrict__ Xg, const ushort_t* __restrict__ W1t,
    const ushort_t* __restrict__ W3t,
    const float* __restrict__ b1, const float* __restrict__ b3,
    const int* __restrict__ counts, const int* __restrict__ offsets,
    ushort_t* __restrict__ H)
{
    __shared__ __align__(16) ushort_t sA[2][4096];
    __shared__ __align__(16) ushort_t sB1[2][4096];
    __shared__ __align__(16) ushort_t sB3[2][4096];

    int tm = blockIdx.x, e = 0, cnt = 0;
    for (; e < NE; ++e) {
        cnt = counts[e];
        int nt = (cnt + 127) >> 7;
        if (tm < nt) break;
        tm -= nt;
    }
    if (e >= NE) return;
    int row0 = offsets[e] + tm * 128;
    int rows_left = cnt - tm * 128;

    int tile_n = blockIdx.y * 128;
    int tid = threadIdx.x, wave = tid >> 6, lane = tid & 63;
    int wm = (wave >> 1) * 64, wn = (wave & 1) * 64;
    int col = lane & 15, quad = lane >> 4;

    const ushort_t* W1e = W1t + (size_t)e * D_FF * D_MODEL;
    const ushort_t* W3e = W3t + (size_t)e * D_FF * D_MODEL;

    // staging geometry: inst s of wave w covers rows w*32+s*16 .. +15
    int lr = lane >> 2, slot = lane & 3;
    int r_s = wave * 32 + lr;                       // s=0 row; s=1 adds 16
    int cchunk = slot ^ ((r_s >> 1) & 3);           // (r+16)>>1 has same &3 -> s=1 identical
    const ushort_t* pA  = Xg  + (size_t)(row0 + r_s) * D_MODEL + cchunk * 8;
    const ushort_t* pB1 = W1e + (size_t)(tile_n + r_s) * D_MODEL + cchunk * 8;
    const ushort_t* pB3 = W3e + (size_t)(tile_n + r_s) * D_MODEL + cchunk * 8;
    const unsigned ldsb = (unsigned)wave * 1024;    // elems; s=1 adds 512
    const size_t rstep = (size_t)16 * D_MODEL;      // +16 rows

    // frag read offsets (elems within one buffer)
    unsigned offA[4], offB[4];
#pragma unroll
    for (int i = 0; i < 4; ++i) {
        int ra = wm + i * 16 + col;
        int rb = wn + i * 16 + col;
        offA[i] = (unsigned)ra * 32 + (unsigned)((quad ^ ((ra >> 1) & 3)) * 8);
        offB[i] = (unsigned)rb * 32 + (unsigned)((quad ^ ((rb >> 1) & 3)) * 8);
    }

    f32x4 acc1[4][4], acc3[4][4];
#pragma unroll
    for (int i = 0; i < 4; ++i)
#pragma unroll
        for (int j = 0; j < 4; ++j) {
            acc1[i][j] = (f32x4){0.f, 0.f, 0.f, 0.f};
            acc3[i][j] = (f32x4){0.f, 0.f, 0.f, 0.f};
        }

    // prologue: k-tile 0 -> buf 0
    async16(pA, sA[0] + ldsb);             async16(pA + rstep, sA[0] + ldsb + 512);
    async16(pB1, sB1[0] + ldsb);           async16(pB1 + rstep, sB1[0] + ldsb + 512);
    async16(pB3, sB3[0] + ldsb);           async16(pB3 + rstep, sB3[0] + ldsb + 512);

    int p = 0;
    for (int it = 0; it < D_MODEL / 32; ++it) {
        __syncthreads();                    // drains buf[p]'s loads
        if (it + 1 < D_MODEL / 32) {
            int ko = (it + 1) * 32;
            int q = p ^ 1;
            async16(pA + ko, sA[q] + ldsb);           async16(pA + ko + rstep, sA[q] + ldsb + 512);
            async16(pB1 + ko, sB1[q] + ldsb);         async16(pB1 + ko + rstep, sB1[q] + ldsb + 512);
            async16(pB3 + ko, sB3[q] + ldsb);         async16(pB3 + ko + rstep, sB3[q] + ldsb + 512);
        }
        bf16x8 u1[4], u3[4];
#pragma unroll
        for (int j = 0; j < 4; ++j) {
            u1[j] = *(const bf16x8*)(sB1[p] + offB[j]);
            u3[j] = *(const bf16x8*)(sB3[p] + offB[j]);
        }
#pragma unroll
        for (int i = 0; i < 4; ++i) {
            bf16x8 a = *(const bf16x8*)(sA[p] + offA[i]);
#pragma unroll
            for (int j = 0; j < 4; ++j) {
                acc1[i][j] = __builtin_amdgcn_mfma_f32_16x16x32_bf16(a, u1[j], acc1[i][j], 0, 0, 0);
                acc3[i][j] = __builtin_amdgcn_mfma_f32_16x16x32_bf16(a, u3[j], acc3[i][j], 0, 0, 0);
            }
        }
        p ^= 1;
    }

#pragma unroll
    for (int j = 0; j < 4; ++j) {
        int n = tile_n + wn + j * 16 + col;
        float bias1 = b1[e * D_FF + n];
        float bias3 = b3[e * D_FF + n];
#pragma unroll
        for (int i = 0; i < 4; ++i) {
            int rbase = wm + i * 16 + quad * 4;
#pragma unroll
            for (int r = 0; r < 4; ++r) {
                int row = rbase + r;
                if (row < rows_left) {
                    float h1 = acc1[i][j][r] + bias1;
                    float h3 = acc3[i][j][r] + bias3;
                    float s = h1 / (1.f + __expf(-h1));   // silu
                    H[(size_t)(row0 + row) * D_FF + n] = f2bf(s * h3);
                }
            }
        }
    }
}

// ---------------- grouped GEMM2 (split-K z=2): out[tok] += w * (H @ W2 + b2) ----------------
__global__ __launch_bounds__(256, 3) void k_gemm2(
    const ushort_t* __restrict__ H, const ushort_t* __restrict__ W2t,
    const float* __restrict__ b2,
    const int* __restrict__ counts, const int* __restrict__ offsets,
    const int* __restrict__ btok, const float* __restrict__ bw,
    float* __restrict__ out)
{
    __shared__ __align__(16) ushort_t sA[2][4096];
    __shared__ __align__(16) ushort_t sB[2][4096];

    int tm = blockIdx.x, e = 0, cnt = 0;
    for (; e < NE; ++e) {
        cnt = counts[e];
        int nt = (cnt + 127) >> 7;
        if (tm < nt) break;
        tm -= nt;
    }
    if (e >= NE) return;
    int row0 = offsets[e] + tm * 128;
    int rows_left = cnt - tm * 128;

    int tile_n = blockIdx.y * 128;
    int zc = blockIdx.z;
    int kz = zc * (D_FF / 2);

    int tid = threadIdx.x, wave = tid >> 6, lane = tid & 63;
    int wm = (wave >> 1) * 64, wn = (wave & 1) * 64;
    int col = lane & 15, quad = lane >> 4;

    const ushort_t* W2e = W2t + (size_t)e * D_MODEL * D_FF;

    int lr = lane >> 2, slot = lane & 3;
    int r_s = wave * 32 + lr;
    int cchunk = slot ^ ((r_s >> 1) & 3);
    const ushort_t* pA = H   + (size_t)(row0 + r_s) * D_FF + kz + cchunk * 8;
    const ushort_t* pB = W2e + (size_t)(tile_n + r_s) * D_FF + kz + cchunk * 8;
    const unsigned ldsb = (unsigned)wave * 1024;
    const size_t rstep = (size_t)16 * D_FF;

    unsigned offA[4], offB[4];
#pragma unroll
    for (int i = 0; i < 4; ++i) {
        int ra = wm + i * 16 + col;
        int rb = wn + i * 16 + col;
        offA[i] = (unsigned)ra * 32 + (unsigned)((quad ^ ((ra >> 1) & 3)) * 8);
        offB[i] = (unsigned)rb * 32 + (unsigned)((quad ^ ((rb >> 1) & 3)) * 8);
    }

    f32x4 acc[4][4];
#pragma unroll
    for (int i = 0; i < 4; ++i)
#pragma unroll
        for (int j = 0; j < 4; ++j) acc[i][j] = (f32x4){0.f, 0.f, 0.f, 0.f};

    async16(pA, sA[0] + ldsb);   async16(pA + rstep, sA[0] + ldsb + 512);
    async16(pB, sB[0] + ldsb);   async16(pB + rstep, sB[0] + ldsb + 512);

    int p = 0;
    const int NIT = (D_FF / 2) / 32;
    for (int it = 0; it < NIT; ++it) {
        __syncthreads();
        if (it + 1 < NIT) {
            int ko = (it + 1) * 32;
            int q = p ^ 1;
            async16(pA + ko, sA[q] + ldsb);   async16(pA + ko + rstep, sA[q] + ldsb + 512);
            async16(pB + ko, sB[q] + ldsb);   async16(pB + ko + rstep, sB[q] + ldsb + 512);
        }
        bf16x8 b[4];
#pragma unroll
        for (int j = 0; j < 4; ++j) b[j] = *(const bf16x8*)(sB[p] + offB[j]);
#pragma unroll
        for (int i = 0; i < 4; ++i) {
            bf16x8 a = *(const bf16x8*)(sA[p] + offA[i]);
#pragma unroll
            for (int j = 0; j < 4; ++j)
                acc[i][j] = __builtin_amdgcn_mfma_f32_16x16x32_bf16(a, b[j], acc[i][j], 0, 0, 0);
        }
        p ^= 1;
    }

    float bias[4];
#pragma unroll
    for (int j = 0; j < 4; ++j)
        bias[j] = (zc == 0) ? b2[e * D_MODEL + tile_n + wn + j * 16 + col] : 0.f;

#pragma unroll
    for (int i = 0; i < 4; ++i) {
        int rbase = wm + i * 16 + quad * 4;
#pragma unroll
        for (int r = 0; r < 4; ++r) {
            int row = rbase + r;
            if (row < rows_left) {
                int g_r = row0 + row;
                int t = btok[g_r];
                float w = bw[g_r];
                float* orow = out + (size_t)t * D_MODEL + tile_n + wn + col;
#pragma unroll
                for (int j = 0; j < 4; ++j)
                    atomicAdd(orow + j * 16, w * (acc[i][j][r] + bias[j]));
            }
        }
    }
}

extern "C" void kernel_launch(void* const* d_in, const int* in_sizes, int n_in,
                              void* d_out, int out_size, void* d_ws, size_t ws_size,
                              hipStream_t stream)
{
    const float* x  = (const float*)d_in[0];
    const float* Wg = (const float*)d_in[1];
    const float* bg = (const float*)d_in[2];
    const float* W1 = (const float*)d_in[3];
    const float* b1 = (const float*)d_in[4];
    const float* W3 = (const float*)d_in[5];
    const float* b3 = (const float*)d_in[6];
    const float* W2 = (const float*)d_in[7];
    const float* b2 = (const float*)d_in[8];
    float* out = (float*)d_out;

    char* ws = (char*)d_ws;
    int*   counts  = (int*)(ws + 0);
    int*   cursors = (int*)(ws + 32);
    int*   offsets = (int*)(ws + 64);
    int*   topi    = (int*)(ws + 256);
    float* topw    = (float*)(ws + 256 + 32768);
    int*   btok    = (int*)(ws + 256 + 65536);
    float* bw      = (float*)(ws + 256 + 98304);
    char* p = ws + 131328;
    ushort_t* Xg  = (ushort_t*)p;  p += (size_t)R_TOT * D_MODEL * 2;      // 16.78 MB
    ushort_t* Hb  = (ushort_t*)p;  p += (size_t)R_TOT * D_FF * 2;         // 67.1 MB
    ushort_t* W1t = (ushort_t*)p;  p += (size_t)NE * D_FF * D_MODEL * 2;  // 67.1 MB
    ushort_t* W3t = (ushort_t*)p;  p += (size_t)NE * D_FF * D_MODEL * 2;  // 67.1 MB
    ushort_t* W2t = (ushort_t*)p;                                          // 67.1 MB

    hipMemsetAsync(ws, 0, 64, stream);                       // counts + cursors
    hipMemsetAsync(d_out, 0, (size_t)out_size * 4, stream);  // atomics accumulate into out

    k_gate<<<dim3(T_TOK / 4), dim3(256), 0, stream>>>(x, Wg, bg, topi, topw, counts);
    k_scan<<<dim3(1), dim3(64), 0, stream>>>(counts, offsets, cursors);
    k_scatter<<<dim3(T_TOK / 256), dim3(256), 0, stream>>>(topi, topw, cursors, btok, bw);
    k_gather<<<dim3(R_TOT), dim3(256), 0, stream>>>(x, btok, Xg);
    k_transpose<<<dim3(D_FF / 64, D_MODEL / 64, NE), dim3(256), 0, stream>>>(W1, W1t, D_MODEL, D_FF);
    k_transpose<<<dim3(D_FF / 64, D_MODEL / 64, NE), dim3(256), 0, stream>>>(W3, W3t, D_MODEL, D_FF);
    k_transpose<<<dim3(D_MODEL / 64, D_FF / 64, NE), dim3(256), 0, stream>>>(W2, W2t, D_FF, D_MODEL);
    k_gemm1<<<dim3(72, D_FF / 128), dim3(256), 0, stream>>>(Xg, W1t, W3t, b1, b3, counts, offsets, Hb);
    k_gemm2<<<dim3(72, D_MODEL / 128, 2), dim3(256), 0, stream>>>(Hb, W2t, b2, counts, offsets, btok, bw, out);
}